// Round 3
// baseline (2775.996 us; speedup 1.0000x reference)
//
#include <hip/hip_runtime.h>
#include <hip/hip_bf16.h>
#include <math.h>

typedef __hip_bfloat16 bf16;

#define BB 4
#define LF 257      // NTOK+1
#define DMODEL 384
#define DIN 768
#define NST 16
#define DTR 24
#define XDB 56      // DTR + 2*N
#define POSROW 128

__device__ __forceinline__ float b2f(bf16 v) { return __bfloat162float(v); }
__device__ __forceinline__ float siluf(float v) { return v / (1.f + __expf(-v)); }
__device__ __forceinline__ float softplusf(float v) {
    return (v > 20.f) ? v : log1pf(__expf(v));
}

// Dual-pointer dtype-agnostic load: pb = bf16 view, pf = f32 view (same
// logical tensor, pre-offset per layer in the right element size). ff selects.
__device__ __forceinline__ float ldv2(const void* pb, const void* pf, size_t i, int ff) {
    return ff ? ((const float*)pf)[i] : b2f(((const bf16*)pb)[i]);
}

// Detect input dtype from Dp (all-ones by construction).
// bf16 ones -> elem0 = 0x3F80 = 1.0 ; f32 ones read as bf16 -> elem0 = 0x0000 = 0.0
__global__ void detect_k(const void* Dp, int* flag) {
    *flag = (b2f(((const bf16*)Dp)[0]) == 1.0f) ? 0 : 1;
}

// ---------------------------------------------------------------------------
// Generic tiled GEMM:  C[m,n] = act( sum_k A[m,k] * W[n,k] + bias[n] )
// A fp32 (workspace), W/bias dual-pointer inputs.
// AMODE: 0 = plain A (lda), 1 = patch gather from depth_seq,
//        2 = flip-add A = Af[m,k] + Ab[flip(m),k]
// SMODE: 0 = plain (+optional bias), 1 = softplus(+bias),
//        2 = accumulate (C += acc, no bias), 3 = patchify store (cls gap + pos)
// ---------------------------------------------------------------------------
template<int AMODE, int SMODE>
__global__ __launch_bounds__(256) void gemm_k(
    const float* __restrict__ A, int lda,
    const void* __restrict__ Wb, const void* __restrict__ Wf,
    const void* __restrict__ biasb, const void* __restrict__ biasf,
    float* __restrict__ Cout,
    int M, int N, int K,
    const void* __restrict__ gAb, const void* __restrict__ gAf, // depth_seq (AMODE 1)
    const float* __restrict__ A2,                               // y_b (AMODE 2)
    const void* __restrict__ posb, const void* __restrict__ posf, // pos_embed (SMODE 3)
    const int* __restrict__ flagp)
{
    const int ff = *flagp;
    __shared__ float As[64][17];
    __shared__ float Ws[64][17];
    const int tid = threadIdx.x;
    const int tx = tid & 15, ty = tid >> 4;
    const int bm = blockIdx.x * 64, bn = blockIdx.y * 64;
    const int lr = tid >> 2;          // 0..63
    const int lc = (tid & 3) * 4;     // 0,4,8,12

    float acc[4][4] = {};

    for (int k0 = 0; k0 < K; k0 += 16) {
        {
            int m = bm + lr;
            #pragma unroll
            for (int u = 0; u < 4; ++u) {
                int k = k0 + lc + u;
                float v = 0.f;
                if (m < M && k < K) {
                    if (AMODE == 0) {
                        v = A[(size_t)m * lda + k];
                    } else if (AMODE == 1) {
                        int b = m >> 8, t = m & 255;
                        int gh = t >> 3, gw = t & 7;
                        int p1 = k >> 4, p2 = k & 15;
                        v = ldv2(gAb, gAf,
                                 (size_t)b * 65536 + gh * 2048 + p1 * 128 + gw * 16 + p2, ff);
                    } else {  // AMODE 2
                        int b = m / LF, l = m - b * LF;
                        v = A[(size_t)m * lda + k] +
                            A2[(size_t)(b * LF + (LF - 1 - l)) * lda + k];
                    }
                }
                As[lr][lc + u] = v;
            }
        }
        {
            int n = bn + lr;
            #pragma unroll
            for (int u = 0; u < 4; ++u) {
                int k = k0 + lc + u;
                Ws[lr][lc + u] = (n < N && k < K) ? ldv2(Wb, Wf, (size_t)n * K + k, ff) : 0.f;
            }
        }
        __syncthreads();
        #pragma unroll
        for (int kk = 0; kk < 16; ++kk) {
            float a[4], w[4];
            #pragma unroll
            for (int i = 0; i < 4; ++i) a[i] = As[ty * 4 + i][kk];
            #pragma unroll
            for (int j = 0; j < 4; ++j) w[j] = Ws[tx * 4 + j][kk];
            #pragma unroll
            for (int i = 0; i < 4; ++i)
                #pragma unroll
                for (int j = 0; j < 4; ++j)
                    acc[i][j] += a[i] * w[j];
        }
        __syncthreads();
    }

    #pragma unroll
    for (int i = 0; i < 4; ++i) {
        int m = bm + ty * 4 + i;
        if (m >= M) continue;
        #pragma unroll
        for (int j = 0; j < 4; ++j) {
            int n = bn + tx * 4 + j;
            if (n >= N) continue;
            float v = acc[i][j];
            if (SMODE == 0) {
                if (biasb) v += ldv2(biasb, biasf, n, ff);
                Cout[(size_t)m * N + n] = v;
            } else if (SMODE == 1) {
                v += ldv2(biasb, biasf, n, ff);
                Cout[(size_t)m * N + n] = softplusf(v);
            } else if (SMODE == 2) {
                Cout[(size_t)m * N + n] += v;
            } else {  // SMODE 3: patchify store
                int b = m >> 8, t = m & 255;
                int l = (t < POSROW) ? t : t + 1;
                v += ldv2(biasb, biasf, n, ff) + ldv2(posb, posf, (size_t)l * DMODEL + n, ff);
                Cout[(size_t)(b * LF + l) * DMODEL + n] = v;
            }
        }
    }
}

// cls row: residual[b, 128, :] = cls + pos[128]
__global__ void cls_k(const void* __restrict__ cls, const void* __restrict__ clsf,
                      const void* __restrict__ pos, const void* __restrict__ posf,
                      float* __restrict__ residual, const int* __restrict__ flagp) {
    const int ff = *flagp;
    int b = blockIdx.x, t = threadIdx.x;
    residual[(size_t)(b * LF + POSROW) * DMODEL + t] =
        ldv2(cls, clsf, t, ff) + ldv2(pos, posf, (size_t)POSROW * DMODEL + t, ff);
}

// row-wise layernorm over 384, 128 threads x 3 elems
__global__ __launch_bounds__(128) void ln_k(const float* __restrict__ X,
                                            const void* __restrict__ wb, const void* __restrict__ wf,
                                            const void* __restrict__ bb, const void* __restrict__ bf,
                                            float* __restrict__ Y,
                                            const int* __restrict__ flagp) {
    const int ff = *flagp;
    int r = blockIdx.x;
    const float* x = X + (size_t)r * DMODEL;
    int t = threadIdx.x;
    float v0 = x[t], v1 = x[t + 128], v2 = x[t + 256];
    float s = v0 + v1 + v2;
    float sq = v0 * v0 + v1 * v1 + v2 * v2;
    #pragma unroll
    for (int o = 32; o > 0; o >>= 1) {
        s += __shfl_down(s, o);
        sq += __shfl_down(sq, o);
    }
    __shared__ float ls[2], lq[2];
    if ((t & 63) == 0) { ls[t >> 6] = s; lq[t >> 6] = sq; }
    __syncthreads();
    float S = ls[0] + ls[1], Q = lq[0] + lq[1];
    float mean = S * (1.f / 384.f);
    float var = Q * (1.f / 384.f) - mean * mean;
    float rs = rsqrtf(var + 1e-5f);
    float* y = Y + (size_t)r * DMODEL;
    y[t]       = (v0 - mean) * rs * ldv2(wb, wf, t, ff)       + ldv2(bb, bf, t, ff);
    y[t + 128] = (v1 - mean) * rs * ldv2(wb, wf, t + 128, ff) + ldv2(bb, bf, t + 128, ff);
    y[t + 256] = (v2 - mean) * rs * ldv2(wb, wf, t + 256, ff) + ldv2(bb, bf, t + 256, ff);
}

// fused fwd+bwd causal depthwise conv (K=4) + SiLU
__global__ __launch_bounds__(256) void conv_k(
    const float* __restrict__ xz,
    const void* __restrict__ cwb, const void* __restrict__ cwf,
    const void* __restrict__ cbb, const void* __restrict__ cbf,
    const void* __restrict__ cwbb, const void* __restrict__ cwbf,
    const void* __restrict__ cbbb, const void* __restrict__ cbbf,
    float* __restrict__ xcf, float* __restrict__ xcb,
    const int* __restrict__ flagp) {
    const int ff = *flagp;
    int g = blockIdx.x * 256 + threadIdx.x;
    if (g >= BB * LF * DIN) return;
    int d = g % DIN;
    int rm = g / DIN;
    int b = rm / LF, l = rm - b * LF;
    const float* xb = xz + (size_t)b * LF * (2 * DIN);
    float wfv[4], wbv[4];
    #pragma unroll
    for (int k = 0; k < 4; ++k) {
        wfv[k] = ldv2(cwb, cwf, d * 4 + k, ff);
        wbv[k] = ldv2(cwbb, cwbf, d * 4 + k, ff);
    }
    float af = ldv2(cbb, cbf, d, ff), ab = ldv2(cbbb, cbbf, d, ff);
    #pragma unroll
    for (int k = 0; k < 4; ++k) {
        int li = l - 3 + k;
        if (li >= 0) {
            af += xb[(size_t)li * (2 * DIN) + d] * wfv[k];
            ab += xb[(size_t)(LF - 1 - li) * (2 * DIN) + d] * wbv[k];
        }
    }
    xcf[(size_t)rm * DIN + d] = siluf(af);
    xcb[(size_t)rm * DIN + d] = siluf(ab);
}

// selective scan, both branches via blockIdx.z; 256 channels/block
__global__ __launch_bounds__(256) void scan_k(
    const float* __restrict__ xcf, const float* __restrict__ dtf,
    const float* __restrict__ xdbf,
    const float* __restrict__ xcb, const float* __restrict__ dtb,
    const float* __restrict__ xdbb,
    const float* __restrict__ xz,
    const void* __restrict__ alfb, const void* __restrict__ alff,
    const void* __restrict__ dpfb, const void* __restrict__ dpff,
    const void* __restrict__ albb, const void* __restrict__ albf,
    const void* __restrict__ dpbb, const void* __restrict__ dpbf,
    float* __restrict__ yf, float* __restrict__ yb,
    const int* __restrict__ flagp) {
    const int ff = *flagp;
    const int br = blockIdx.z;
    const int b = blockIdx.y;
    const int d = blockIdx.x * 256 + threadIdx.x;
    const float* xc  = br ? xcb  : xcf;
    const float* dt  = br ? dtb  : dtf;
    const float* xdb = br ? xdbb : xdbf;
    const void* Ab = br ? albb : alfb;
    const void* Af = br ? albf : alff;
    const void* Db = br ? dpbb : dpfb;
    const void* Df = br ? dpbf : dpff;
    float* yo        = br ? yb   : yf;

    float An[NST], h[NST];
    #pragma unroll
    for (int n = 0; n < NST; ++n) {
        An[n] = -__expf(ldv2(Ab, Af, (size_t)d * NST + n, ff));
        h[n] = 0.f;
    }
    float Dv = ldv2(Db, Df, d, ff);

    __shared__ float sBC[32];
    for (int l = 0; l < LF; ++l) {
        int row = b * LF + l;
        float dtv = dt[(size_t)row * DIN + d];
        float xcv = xc[(size_t)row * DIN + d];
        int zl = br ? (LF - 1 - l) : l;
        float zv = xz[(size_t)(b * LF + zl) * (2 * DIN) + DIN + d];
        if (threadIdx.x < 32)
            sBC[threadIdx.x] = xdb[(size_t)row * XDB + DTR + threadIdx.x];
        __syncthreads();
        float dtx = dtv * xcv;
        float acc = 0.f;
        #pragma unroll
        for (int n = 0; n < NST; ++n) {
            float dA = __expf(dtv * An[n]);
            h[n] = dA * h[n] + dtx * sBC[n];
            acc += h[n] * sBC[NST + n];
        }
        float yv = acc + xcv * Dv;
        yo[(size_t)row * DIN + d] = yv * siluf(zv);
        __syncthreads();
    }
}

// final LN(row POS) + command MLP + add -> f32 out (reference output dtype)
__global__ __launch_bounds__(384) void final_k(
    const float* __restrict__ residual,
    const void* __restrict__ lnw, const void* __restrict__ lnb,
    const void* __restrict__ sv, const void* __restrict__ act,
    const void* __restrict__ cw1, const void* __restrict__ cb1,
    const void* __restrict__ cw2, const void* __restrict__ cb2,
    float* __restrict__ out, const int* __restrict__ flagp) {
    const int ff = *flagp;
    int b = blockIdx.x, t = threadIdx.x;
    const float* x = residual + (size_t)(b * LF + POSROW) * DMODEL;
    float v = x[t];
    float s = v, sq = v * v;
    #pragma unroll
    for (int o = 32; o > 0; o >>= 1) {
        s += __shfl_down(s, o);
        sq += __shfl_down(sq, o);
    }
    __shared__ float ls[6], lq[6], hid[DMODEL], cmdin[20];
    if ((t & 63) == 0) { ls[t >> 6] = s; lq[t >> 6] = sq; }
    if (t < 20) cmdin[t] = (t < 16) ? ldv2(sv, sv, b * 16 + t, ff)
                                    : ldv2(act, act, b * 4 + t - 16, ff);
    __syncthreads();
    float S = 0.f, Q = 0.f;
    #pragma unroll
    for (int w = 0; w < 6; ++w) { S += ls[w]; Q += lq[w]; }
    float mean = S * (1.f / 384.f);
    float var = Q * (1.f / 384.f) - mean * mean;
    float rs = rsqrtf(var + 1e-5f);
    float vis = (v - mean) * rs * ldv2(lnw, lnw, t, ff) + ldv2(lnb, lnb, t, ff);
    float a1 = ldv2(cb1, cb1, t, ff);
    #pragma unroll
    for (int k = 0; k < 20; ++k) a1 += cmdin[k] * ldv2(cw1, cw1, t * 20 + k, ff);
    hid[t] = fmaxf(a1, 0.f);
    __syncthreads();
    float a2 = ldv2(cb2, cb2, t, ff);
    for (int k = 0; k < DMODEL; ++k) a2 += hid[k] * ldv2(cw2, cw2, t * DMODEL + k, ff);
    out[b * DMODEL + t] = vis + a2;
}

extern "C" void kernel_launch(void* const* d_in, const int* in_sizes, int n_in,
                              void* d_out, int out_size, void* d_ws, size_t ws_size,
                              hipStream_t stream) {
    const void* depth_seq = d_in[0];
    const void* state_vec = d_in[1];
    const void* action    = d_in[2];
    const void* patch_w   = d_in[3];
    const void* patch_b   = d_in[4];
    const void* cls_token = d_in[5];
    const void* pos_embed = d_in[6];
    const void* ln_w      = d_in[7];
    const void* ln_b      = d_in[8];
    const void* in_proj_w = d_in[9];
    const void* conv_w    = d_in[10];
    const void* conv_b    = d_in[11];
    const void* conv_wb   = d_in[12];
    const void* conv_bb   = d_in[13];
    const void* xproj_w   = d_in[14];
    const void* xproj_wb  = d_in[15];
    const void* dtproj_w  = d_in[16];
    const void* dtproj_b  = d_in[17];
    const void* dtproj_wb = d_in[18];
    const void* dtproj_bb = d_in[19];
    const void* A_log     = d_in[20];
    const void* A_logb    = d_in[21];
    const void* Dp        = d_in[22];
    const void* Dpb       = d_in[23];
    const void* out_w     = d_in[24];
    const void* lnf_w     = d_in[25];
    const void* lnf_b     = d_in[26];
    const void* cw1       = d_in[27];
    const void* cb1       = d_in[28];
    const void* cw2       = d_in[29];
    const void* cb2       = d_in[30];

    const int M = BB * LF;  // 1028
    float* ws = (float*)d_ws;
    size_t o = 0;
    float* residual = ws + o; o += (size_t)M * DMODEL;
    float* h_ln     = ws + o; o += (size_t)M * DMODEL;
    float* xz       = ws + o; o += (size_t)M * 2 * DIN;
    float* xcf      = ws + o; o += (size_t)M * DIN;
    float* xcb      = ws + o; o += (size_t)M * DIN;
    float* xdbf     = ws + o; o += (size_t)M * XDB;
    float* xdbb     = ws + o; o += (size_t)M * XDB;
    float* dtf      = ws + o; o += (size_t)M * DIN;
    float* dtb      = ws + o; o += (size_t)M * DIN;
    float* yfb      = ws + o; o += (size_t)M * DIN;
    float* ybb      = ws + o; o += (size_t)M * DIN;
    int* dflag      = (int*)(ws + o);
    (void)ws_size; (void)in_sizes; (void)n_in; (void)out_size;

    // byte-offset helpers for per-layer weights, both dtype views
    auto B2 = [](const void* p, size_t elems) { return (const void*)((const char*)p + elems * 2); };
    auto F4 = [](const void* p, size_t elems) { return (const void*)((const char*)p + elems * 4); };

    detect_k<<<1, 1, 0, stream>>>(Dp, dflag);

    // patchify -> residual (with bias + pos, cls gap)
    gemm_k<1, 3><<<dim3(16, 6), 256, 0, stream>>>(
        nullptr, 0, patch_w, patch_w, patch_b, patch_b, residual, 1024, DMODEL, 256,
        depth_seq, depth_seq, nullptr, pos_embed, pos_embed, dflag);
    cls_k<<<BB, DMODEL, 0, stream>>>(cls_token, cls_token, pos_embed, pos_embed,
                                     residual, dflag);

    for (int i = 0; i < 4; ++i) {
        const size_t eD   = (size_t)i * DMODEL;
        const size_t eIN  = (size_t)i * 2 * DIN * DMODEL;
        const size_t eCW  = (size_t)i * DIN * 4;
        const size_t eCB  = (size_t)i * DIN;
        const size_t eXW  = (size_t)i * XDB * DIN;
        const size_t eDTW = (size_t)i * DIN * DTR;
        const size_t eAL  = (size_t)i * DIN * NST;
        const size_t eOW  = (size_t)i * DMODEL * DIN;

        ln_k<<<M, 128, 0, stream>>>(residual,
            B2(ln_w, eD), F4(ln_w, eD), B2(ln_b, eD), F4(ln_b, eD), h_ln, dflag);
        // in_proj: (1028 x 384) @ (384 x 1536)^T
        gemm_k<0, 0><<<dim3(17, 24), 256, 0, stream>>>(
            h_ln, DMODEL, B2(in_proj_w, eIN), F4(in_proj_w, eIN), nullptr, nullptr,
            xz, M, 2 * DIN, DMODEL, nullptr, nullptr, nullptr, nullptr, nullptr, dflag);
        conv_k<<<(BB * LF * DIN) / 256, 256, 0, stream>>>(
            xz, B2(conv_w, eCW), F4(conv_w, eCW), B2(conv_b, eCB), F4(conv_b, eCB),
            B2(conv_wb, eCW), F4(conv_wb, eCW), B2(conv_bb, eCB), F4(conv_bb, eCB),
            xcf, xcb, dflag);
        // x_proj: (1028 x 768) @ (768 x 56)^T
        gemm_k<0, 0><<<dim3(17, 1), 256, 0, stream>>>(
            xcf, DIN, B2(xproj_w, eXW), F4(xproj_w, eXW), nullptr, nullptr,
            xdbf, M, XDB, DIN, nullptr, nullptr, nullptr, nullptr, nullptr, dflag);
        gemm_k<0, 0><<<dim3(17, 1), 256, 0, stream>>>(
            xcb, DIN, B2(xproj_wb, eXW), F4(xproj_wb, eXW), nullptr, nullptr,
            xdbb, M, XDB, DIN, nullptr, nullptr, nullptr, nullptr, nullptr, dflag);
        // dt: (1028 x 24) @ (24 x 768)^T + softplus
        gemm_k<0, 1><<<dim3(17, 12), 256, 0, stream>>>(
            xdbf, XDB, B2(dtproj_w, eDTW), F4(dtproj_w, eDTW),
            B2(dtproj_b, eCB), F4(dtproj_b, eCB),
            dtf, M, DIN, DTR, nullptr, nullptr, nullptr, nullptr, nullptr, dflag);
        gemm_k<0, 1><<<dim3(17, 12), 256, 0, stream>>>(
            xdbb, XDB, B2(dtproj_wb, eDTW), F4(dtproj_wb, eDTW),
            B2(dtproj_bb, eCB), F4(dtproj_bb, eCB),
            dtb, M, DIN, DTR, nullptr, nullptr, nullptr, nullptr, nullptr, dflag);
        // selective scan, both branches
        scan_k<<<dim3(3, BB, 2), 256, 0, stream>>>(
            xcf, dtf, xdbf, xcb, dtb, xdbb, xz,
            B2(A_log, eAL), F4(A_log, eAL), B2(Dp, eCB), F4(Dp, eCB),
            B2(A_logb, eAL), F4(A_logb, eAL), B2(Dpb, eCB), F4(Dpb, eCB),
            yfb, ybb, dflag);
        // out_proj with fused flip-add, residual +=
        gemm_k<2, 2><<<dim3(17, 6), 256, 0, stream>>>(
            yfb, DIN, B2(out_w, eOW), F4(out_w, eOW), nullptr, nullptr,
            residual, M, DMODEL, DIN, nullptr, nullptr, ybb, nullptr, nullptr, dflag);
    }

    final_k<<<BB, DMODEL, 0, stream>>>(
        residual, lnf_w, lnf_b, state_vec, action, cw1, cb1, cw2, cb2,
        (float*)d_out, dflag);
}

// Round 4
// 2250.888 us; speedup vs baseline: 1.2333x; 1.2333x over previous
//
#include <hip/hip_runtime.h>
#include <hip/hip_bf16.h>
#include <math.h>

typedef __hip_bfloat16 bf16;

#define BB 4
#define LF 257      // NTOK+1
#define DMODEL 384
#define DIN 768
#define NST 16
#define DTR 24
#define XDB 56      // DTR + 2*N
#define POSROW 128

__device__ __forceinline__ float b2f(bf16 v) { return __bfloat162float(v); }
__device__ __forceinline__ float siluf(float v) { return v / (1.f + __expf(-v)); }
__device__ __forceinline__ float softplusf(float v) {
    return (v > 20.f) ? v : log1pf(__expf(v));
}

// Dual-pointer dtype-agnostic load: pb = bf16 view, pf = f32 view. ff selects.
__device__ __forceinline__ float ldv2(const void* pb, const void* pf, size_t i, int ff) {
    return ff ? ((const float*)pf)[i] : b2f(((const bf16*)pb)[i]);
}

// Detect input dtype from Dp (all-ones by construction).
__global__ void detect_k(const void* Dp, int* flag) {
    *flag = (b2f(((const bf16*)Dp)[0]) == 1.0f) ? 0 : 1;
}

// ---------------------------------------------------------------------------
// Tiled GEMM:  C[m,n] = act( sum_k A[m,k] * W[n,k] + bias[n] )
// LDS tiles stored transposed [k][m] (stride 68: float4-aligned rows, 2-way
// bank aliasing only) so the inner loop is 2x ds_read_b128 + 16 FMA.
// AMODE: 0 plain A, 1 patch gather, 2 flip-add.  SMODE: 0 plain(+bias),
// 1 softplus(+bias), 2 accumulate, 3 patchify store (cls gap + pos).
// ---------------------------------------------------------------------------
template<int AMODE, int SMODE>
__global__ __launch_bounds__(256) void gemm_k(
    const float* __restrict__ A, int lda,
    const void* __restrict__ Wb, const void* __restrict__ Wf,
    const void* __restrict__ biasb, const void* __restrict__ biasf,
    float* __restrict__ Cout,
    int M, int N, int K,
    const void* __restrict__ gAb, const void* __restrict__ gAf,
    const float* __restrict__ A2,
    const void* __restrict__ posb, const void* __restrict__ posf,
    const int* __restrict__ flagp)
{
    const int ff = *flagp;
    __shared__ float As[16][68];
    __shared__ float Ws[16][68];
    const int tid = threadIdx.x;
    const int tx = tid & 15, ty = tid >> 4;
    const int bm = blockIdx.x * 64, bn = blockIdx.y * 64;
    const int lr = tid >> 2;          // 0..63  (m/n within tile)
    const int lc = (tid & 3) * 4;     // 0,4,8,12 (k base within tile)

    float acc[4][4] = {};

    for (int k0 = 0; k0 < K; k0 += 16) {
        {
            int m = bm + lr;
            #pragma unroll
            for (int u = 0; u < 4; ++u) {
                int k = k0 + lc + u;
                float v = 0.f;
                if (m < M && k < K) {
                    if (AMODE == 0) {
                        v = A[(size_t)m * lda + k];
                    } else if (AMODE == 1) {
                        int b = m >> 8, t = m & 255;
                        int gh = t >> 3, gw = t & 7;
                        int p1 = k >> 4, p2 = k & 15;
                        v = ldv2(gAb, gAf,
                                 (size_t)b * 65536 + gh * 2048 + p1 * 128 + gw * 16 + p2, ff);
                    } else {  // AMODE 2
                        int b = m / LF, l = m - b * LF;
                        v = A[(size_t)m * lda + k] +
                            A2[(size_t)(b * LF + (LF - 1 - l)) * lda + k];
                    }
                }
                As[lc + u][lr] = v;
            }
        }
        {
            int n = bn + lr;
            #pragma unroll
            for (int u = 0; u < 4; ++u) {
                int k = k0 + lc + u;
                Ws[lc + u][lr] = (n < N && k < K) ? ldv2(Wb, Wf, (size_t)n * K + k, ff) : 0.f;
            }
        }
        __syncthreads();
        #pragma unroll
        for (int kk = 0; kk < 16; ++kk) {
            float a[4], w[4];
            *(float4*)a = *(const float4*)&As[kk][ty * 4];
            *(float4*)w = *(const float4*)&Ws[kk][tx * 4];
            #pragma unroll
            for (int i = 0; i < 4; ++i)
                #pragma unroll
                for (int j = 0; j < 4; ++j)
                    acc[i][j] += a[i] * w[j];
        }
        __syncthreads();
    }

    #pragma unroll
    for (int i = 0; i < 4; ++i) {
        int m = bm + ty * 4 + i;
        if (m >= M) continue;
        #pragma unroll
        for (int j = 0; j < 4; ++j) {
            int n = bn + tx * 4 + j;
            if (n >= N) continue;
            float v = acc[i][j];
            if (SMODE == 0) {
                if (biasb) v += ldv2(biasb, biasf, n, ff);
                Cout[(size_t)m * N + n] = v;
            } else if (SMODE == 1) {
                v += ldv2(biasb, biasf, n, ff);
                Cout[(size_t)m * N + n] = softplusf(v);
            } else if (SMODE == 2) {
                Cout[(size_t)m * N + n] += v;
            } else {  // SMODE 3: patchify store
                int b = m >> 8, t = m & 255;
                int l = (t < POSROW) ? t : t + 1;
                v += ldv2(biasb, biasf, n, ff) + ldv2(posb, posf, (size_t)l * DMODEL + n, ff);
                Cout[(size_t)(b * LF + l) * DMODEL + n] = v;
            }
        }
    }
}

// cls row: residual[b, 128, :] = cls + pos[128]
__global__ void cls_k(const void* __restrict__ cls, const void* __restrict__ clsf,
                      const void* __restrict__ pos, const void* __restrict__ posf,
                      float* __restrict__ residual, const int* __restrict__ flagp) {
    const int ff = *flagp;
    int b = blockIdx.x, t = threadIdx.x;
    residual[(size_t)(b * LF + POSROW) * DMODEL + t] =
        ldv2(cls, clsf, t, ff) + ldv2(pos, posf, (size_t)POSROW * DMODEL + t, ff);
}

// row-wise layernorm over 384, 128 threads x 3 elems
__global__ __launch_bounds__(128) void ln_k(const float* __restrict__ X,
                                            const void* __restrict__ wb, const void* __restrict__ wf,
                                            const void* __restrict__ bb, const void* __restrict__ bf,
                                            float* __restrict__ Y,
                                            const int* __restrict__ flagp) {
    const int ff = *flagp;
    int r = blockIdx.x;
    const float* x = X + (size_t)r * DMODEL;
    int t = threadIdx.x;
    float v0 = x[t], v1 = x[t + 128], v2 = x[t + 256];
    float s = v0 + v1 + v2;
    float sq = v0 * v0 + v1 * v1 + v2 * v2;
    #pragma unroll
    for (int o = 32; o > 0; o >>= 1) {
        s += __shfl_down(s, o);
        sq += __shfl_down(sq, o);
    }
    __shared__ float ls[2], lq[2];
    if ((t & 63) == 0) { ls[t >> 6] = s; lq[t >> 6] = sq; }
    __syncthreads();
    float S = ls[0] + ls[1], Q = lq[0] + lq[1];
    float mean = S * (1.f / 384.f);
    float var = Q * (1.f / 384.f) - mean * mean;
    float rs = rsqrtf(var + 1e-5f);
    float* y = Y + (size_t)r * DMODEL;
    y[t]       = (v0 - mean) * rs * ldv2(wb, wf, t, ff)       + ldv2(bb, bf, t, ff);
    y[t + 128] = (v1 - mean) * rs * ldv2(wb, wf, t + 128, ff) + ldv2(bb, bf, t + 128, ff);
    y[t + 256] = (v2 - mean) * rs * ldv2(wb, wf, t + 256, ff) + ldv2(bb, bf, t + 256, ff);
}

// fused fwd+bwd causal depthwise conv (K=4) + SiLU
__global__ __launch_bounds__(256) void conv_k(
    const float* __restrict__ xz,
    const void* __restrict__ cwb, const void* __restrict__ cwf,
    const void* __restrict__ cbb, const void* __restrict__ cbf,
    const void* __restrict__ cwbb, const void* __restrict__ cwbf,
    const void* __restrict__ cbbb, const void* __restrict__ cbbf,
    float* __restrict__ xcf, float* __restrict__ xcb,
    const int* __restrict__ flagp) {
    const int ff = *flagp;
    int g = blockIdx.x * 256 + threadIdx.x;
    if (g >= BB * LF * DIN) return;
    int d = g % DIN;
    int rm = g / DIN;
    int b = rm / LF, l = rm - b * LF;
    const float* xb = xz + (size_t)b * LF * (2 * DIN);
    float wfv[4], wbv[4];
    #pragma unroll
    for (int k = 0; k < 4; ++k) {
        wfv[k] = ldv2(cwb, cwf, d * 4 + k, ff);
        wbv[k] = ldv2(cwbb, cwbf, d * 4 + k, ff);
    }
    float af = ldv2(cbb, cbf, d, ff), ab = ldv2(cbbb, cbbf, d, ff);
    #pragma unroll
    for (int k = 0; k < 4; ++k) {
        int li = l - 3 + k;
        if (li >= 0) {
            af += xb[(size_t)li * (2 * DIN) + d] * wfv[k];
            ab += xb[(size_t)(LF - 1 - li) * (2 * DIN) + d] * wbv[k];
        }
    }
    xcf[(size_t)rm * DIN + d] = siluf(af);
    xcb[(size_t)rm * DIN + d] = siluf(ab);
}

// selective scan, both branches via blockIdx.z; 256 channels/block.
// Software-pipelined in chunks of 8 steps: 25 independent global loads per
// chunk (dt/xc/z x8 + one B/C stage), double-buffered LDS, ONE barrier per
// chunk instead of 2 barriers + serialized loads per step.
#define SCH 8
__global__ __launch_bounds__(256) void scan_k(
    const float* __restrict__ xcf, const float* __restrict__ dtf,
    const float* __restrict__ xdbf,
    const float* __restrict__ xcb, const float* __restrict__ dtb,
    const float* __restrict__ xdbb,
    const float* __restrict__ xz,
    const void* __restrict__ alfb, const void* __restrict__ alff,
    const void* __restrict__ dpfb, const void* __restrict__ dpff,
    const void* __restrict__ albb, const void* __restrict__ albf,
    const void* __restrict__ dpbb, const void* __restrict__ dpbf,
    float* __restrict__ yf, float* __restrict__ yb,
    const int* __restrict__ flagp) {
    const int ff = *flagp;
    const int br = blockIdx.z;
    const int b = blockIdx.y;
    const int t = threadIdx.x;
    const int d = blockIdx.x * 256 + t;
    const float* xc  = br ? xcb  : xcf;
    const float* dt  = br ? dtb  : dtf;
    const float* xdb = br ? xdbb : xdbf;
    const void* Ab = br ? albb : alfb;
    const void* Af = br ? albf : alff;
    const void* Db = br ? dpbb : dpfb;
    const void* Df = br ? dpbf : dpff;
    float* yo        = br ? yb   : yf;

    float An[NST], h[NST];
    #pragma unroll
    for (int n = 0; n < NST; ++n) {
        An[n] = -__expf(ldv2(Ab, Af, (size_t)d * NST + n, ff));
        h[n] = 0.f;
    }
    float Dv = ldv2(Db, Df, d, ff);

    __shared__ float sBC[2][SCH][32];
    const int ss = t >> 5;          // 0..7: step this thread stages
    const int sj = t & 31;          // 0..31: B/C element

    int buf = 0;
    for (int c0 = 0; c0 < LF; c0 += SCH, buf ^= 1) {
        const int steps = (LF - c0 < SCH) ? (LF - c0) : SCH;
        float dtv[SCH], xcv[SCH], zvv[SCH];
        #pragma unroll
        for (int s = 0; s < SCH; ++s) {
            if (s < steps) {
                int row = b * LF + c0 + s;
                dtv[s] = dt[(size_t)row * DIN + d];
                xcv[s] = xc[(size_t)row * DIN + d];
                int zl = br ? (LF - 1 - (c0 + s)) : (c0 + s);
                zvv[s] = xz[(size_t)(b * LF + zl) * (2 * DIN) + DIN + d];
            }
        }
        if (ss < steps)
            sBC[buf][ss][sj] = xdb[(size_t)(b * LF + c0 + ss) * XDB + DTR + sj];
        __syncthreads();
        for (int s = 0; s < steps; ++s) {
            float dtx = dtv[s] * xcv[s];
            float acc = 0.f;
            #pragma unroll
            for (int n = 0; n < NST; ++n) {
                float dA = __expf(dtv[s] * An[n]);
                h[n] = dA * h[n] + dtx * sBC[buf][s][n];
                acc += h[n] * sBC[buf][s][NST + n];
            }
            yo[(size_t)(b * LF + c0 + s) * DIN + d] = (acc + xcv[s] * Dv) * siluf(zvv[s]);
        }
    }
}

// final LN(row POS) + command MLP + add -> f32 out
__global__ __launch_bounds__(384) void final_k(
    const float* __restrict__ residual,
    const void* __restrict__ lnw, const void* __restrict__ lnb,
    const void* __restrict__ sv, const void* __restrict__ act,
    const void* __restrict__ cw1, const void* __restrict__ cb1,
    const void* __restrict__ cw2, const void* __restrict__ cb2,
    float* __restrict__ out, const int* __restrict__ flagp) {
    const int ff = *flagp;
    int b = blockIdx.x, t = threadIdx.x;
    const float* x = residual + (size_t)(b * LF + POSROW) * DMODEL;
    float v = x[t];
    float s = v, sq = v * v;
    #pragma unroll
    for (int o = 32; o > 0; o >>= 1) {
        s += __shfl_down(s, o);
        sq += __shfl_down(sq, o);
    }
    __shared__ float ls[6], lq[6], hid[DMODEL], cmdin[20];
    if ((t & 63) == 0) { ls[t >> 6] = s; lq[t >> 6] = sq; }
    if (t < 20) cmdin[t] = (t < 16) ? ldv2(sv, sv, b * 16 + t, ff)
                                    : ldv2(act, act, b * 4 + t - 16, ff);
    __syncthreads();
    float S = 0.f, Q = 0.f;
    #pragma unroll
    for (int w = 0; w < 6; ++w) { S += ls[w]; Q += lq[w]; }
    float mean = S * (1.f / 384.f);
    float var = Q * (1.f / 384.f) - mean * mean;
    float rs = rsqrtf(var + 1e-5f);
    float vis = (v - mean) * rs * ldv2(lnw, lnw, t, ff) + ldv2(lnb, lnb, t, ff);
    float a1 = ldv2(cb1, cb1, t, ff);
    #pragma unroll
    for (int k = 0; k < 20; ++k) a1 += cmdin[k] * ldv2(cw1, cw1, t * 20 + k, ff);
    hid[t] = fmaxf(a1, 0.f);
    __syncthreads();
    float a2 = ldv2(cb2, cb2, t, ff);
    for (int k = 0; k < DMODEL; ++k) a2 += hid[k] * ldv2(cw2, cw2, t * DMODEL + k, ff);
    out[b * DMODEL + t] = vis + a2;
}

extern "C" void kernel_launch(void* const* d_in, const int* in_sizes, int n_in,
                              void* d_out, int out_size, void* d_ws, size_t ws_size,
                              hipStream_t stream) {
    const void* depth_seq = d_in[0];
    const void* state_vec = d_in[1];
    const void* action    = d_in[2];
    const void* patch_w   = d_in[3];
    const void* patch_b   = d_in[4];
    const void* cls_token = d_in[5];
    const void* pos_embed = d_in[6];
    const void* ln_w      = d_in[7];
    const void* ln_b      = d_in[8];
    const void* in_proj_w = d_in[9];
    const void* conv_w    = d_in[10];
    const void* conv_b    = d_in[11];
    const void* conv_wb   = d_in[12];
    const void* conv_bb   = d_in[13];
    const void* xproj_w   = d_in[14];
    const void* xproj_wb  = d_in[15];
    const void* dtproj_w  = d_in[16];
    const void* dtproj_b  = d_in[17];
    const void* dtproj_wb = d_in[18];
    const void* dtproj_bb = d_in[19];
    const void* A_log     = d_in[20];
    const void* A_logb    = d_in[21];
    const void* Dp        = d_in[22];
    const void* Dpb       = d_in[23];
    const void* out_w     = d_in[24];
    const void* lnf_w     = d_in[25];
    const void* lnf_b     = d_in[26];
    const void* cw1       = d_in[27];
    const void* cb1       = d_in[28];
    const void* cw2       = d_in[29];
    const void* cb2       = d_in[30];

    const int M = BB * LF;  // 1028
    float* ws = (float*)d_ws;
    size_t o = 0;
    float* residual = ws + o; o += (size_t)M * DMODEL;
    float* h_ln     = ws + o; o += (size_t)M * DMODEL;
    float* xz       = ws + o; o += (size_t)M * 2 * DIN;
    float* xcf      = ws + o; o += (size_t)M * DIN;
    float* xcb      = ws + o; o += (size_t)M * DIN;
    float* xdbf     = ws + o; o += (size_t)M * XDB;
    float* xdbb     = ws + o; o += (size_t)M * XDB;
    float* dtf      = ws + o; o += (size_t)M * DIN;
    float* dtb      = ws + o; o += (size_t)M * DIN;
    float* yfb      = ws + o; o += (size_t)M * DIN;
    float* ybb      = ws + o; o += (size_t)M * DIN;
    int* dflag      = (int*)(ws + o);
    (void)ws_size; (void)in_sizes; (void)n_in; (void)out_size;

    auto B2 = [](const void* p, size_t elems) { return (const void*)((const char*)p + elems * 2); };
    auto F4 = [](const void* p, size_t elems) { return (const void*)((const char*)p + elems * 4); };

    detect_k<<<1, 1, 0, stream>>>(Dp, dflag);

    gemm_k<1, 3><<<dim3(16, 6), 256, 0, stream>>>(
        nullptr, 0, patch_w, patch_w, patch_b, patch_b, residual, 1024, DMODEL, 256,
        depth_seq, depth_seq, nullptr, pos_embed, pos_embed, dflag);
    cls_k<<<BB, DMODEL, 0, stream>>>(cls_token, cls_token, pos_embed, pos_embed,
                                     residual, dflag);

    for (int i = 0; i < 4; ++i) {
        const size_t eD   = (size_t)i * DMODEL;
        const size_t eIN  = (size_t)i * 2 * DIN * DMODEL;
        const size_t eCW  = (size_t)i * DIN * 4;
        const size_t eCB  = (size_t)i * DIN;
        const size_t eXW  = (size_t)i * XDB * DIN;
        const size_t eDTW = (size_t)i * DIN * DTR;
        const size_t eAL  = (size_t)i * DIN * NST;
        const size_t eOW  = (size_t)i * DMODEL * DIN;

        ln_k<<<M, 128, 0, stream>>>(residual,
            B2(ln_w, eD), F4(ln_w, eD), B2(ln_b, eD), F4(ln_b, eD), h_ln, dflag);
        gemm_k<0, 0><<<dim3(17, 24), 256, 0, stream>>>(
            h_ln, DMODEL, B2(in_proj_w, eIN), F4(in_proj_w, eIN), nullptr, nullptr,
            xz, M, 2 * DIN, DMODEL, nullptr, nullptr, nullptr, nullptr, nullptr, dflag);
        conv_k<<<(BB * LF * DIN) / 256, 256, 0, stream>>>(
            xz, B2(conv_w, eCW), F4(conv_w, eCW), B2(conv_b, eCB), F4(conv_b, eCB),
            B2(conv_wb, eCW), F4(conv_wb, eCW), B2(conv_bb, eCB), F4(conv_bb, eCB),
            xcf, xcb, dflag);
        gemm_k<0, 0><<<dim3(17, 1), 256, 0, stream>>>(
            xcf, DIN, B2(xproj_w, eXW), F4(xproj_w, eXW), nullptr, nullptr,
            xdbf, M, XDB, DIN, nullptr, nullptr, nullptr, nullptr, nullptr, dflag);
        gemm_k<0, 0><<<dim3(17, 1), 256, 0, stream>>>(
            xcb, DIN, B2(xproj_wb, eXW), F4(xproj_wb, eXW), nullptr, nullptr,
            xdbb, M, XDB, DIN, nullptr, nullptr, nullptr, nullptr, nullptr, dflag);
        gemm_k<0, 1><<<dim3(17, 12), 256, 0, stream>>>(
            xdbf, XDB, B2(dtproj_w, eDTW), F4(dtproj_w, eDTW),
            B2(dtproj_b, eCB), F4(dtproj_b, eCB),
            dtf, M, DIN, DTR, nullptr, nullptr, nullptr, nullptr, nullptr, dflag);
        gemm_k<0, 1><<<dim3(17, 12), 256, 0, stream>>>(
            xdbb, XDB, B2(dtproj_wb, eDTW), F4(dtproj_wb, eDTW),
            B2(dtproj_bb, eCB), F4(dtproj_bb, eCB),
            dtb, M, DIN, DTR, nullptr, nullptr, nullptr, nullptr, nullptr, dflag);
        scan_k<<<dim3(3, BB, 2), 256, 0, stream>>>(
            xcf, dtf, xdbf, xcb, dtb, xdbb, xz,
            B2(A_log, eAL), F4(A_log, eAL), B2(Dp, eCB), F4(Dp, eCB),
            B2(A_logb, eAL), F4(A_logb, eAL), B2(Dpb, eCB), F4(Dpb, eCB),
            yfb, ybb, dflag);
        gemm_k<2, 2><<<dim3(17, 6), 256, 0, stream>>>(
            yfb, DIN, B2(out_w, eOW), F4(out_w, eOW), nullptr, nullptr,
            residual, M, DMODEL, DIN, nullptr, nullptr, ybb, nullptr, nullptr, dflag);
    }

    final_k<<<BB, DMODEL, 0, stream>>>(
        residual, lnf_w, lnf_b, state_vec, action, cw1, cb1, cw2, cb2,
        (float*)d_out, dflag);
}

// Round 5
// 1334.335 us; speedup vs baseline: 2.0804x; 1.6869x over previous
//
#include <hip/hip_runtime.h>
#include <hip/hip_bf16.h>
#include <math.h>

#define BB 4
#define LF 257      // NTOK+1
#define DMODEL 384
#define DIN 768
#define NST 16
#define DTR 24
#define XDB 56      // DTR + 2*N
#define POSROW 128

__device__ __forceinline__ float siluf(float v) { return v / (1.f + __expf(-v)); }
__device__ __forceinline__ float softplusf(float v) {
    return (v > 20.f) ? v : log1pf(__expf(v));
}

// ---------------------------------------------------------------------------
// Tiled GEMM:  C[m,n] = act( sum_k A[m,k] * W[n,k] + bias[n] )
// f32 inputs. LDS tiles transposed [k][m] (stride 68), float4 staging loads,
// register double-buffer of the next k-tile overlapping global latency with
// the FMA phase (loads issue before compute; barrier drain finds them done).
// AMODE: 0 plain A, 1 patch gather, 2 flip-add.  SMODE: 0 plain(+bias),
// 1 softplus(+bias), 2 accumulate, 3 patchify store (cls gap + pos).
// All K and lda are multiples of 4, k stays 4-aligned => quad in-bounds iff
// its first element is.
// ---------------------------------------------------------------------------
template<int AMODE, int SMODE>
__global__ __launch_bounds__(256) void gemm_k(
    const float* __restrict__ A, int lda,
    const float* __restrict__ W,
    const float* __restrict__ bias,
    float* __restrict__ Cout,
    int M, int N, int K,
    const float* __restrict__ gA,   // depth_seq (AMODE 1)
    const float* __restrict__ A2,   // y_b (AMODE 2)
    const float* __restrict__ pos)  // pos_embed (SMODE 3)
{
    __shared__ float As[16][68];
    __shared__ float Ws[16][68];
    const int tid = threadIdx.x;
    const int tx = tid & 15, ty = tid >> 4;
    const int bm = blockIdx.x * 64, bn = blockIdx.y * 64;
    const int lr = tid >> 2;          // 0..63  (m/n within tile)
    const int lc = (tid & 3) * 4;     // 0,4,8,12 (k base within tile)
    const int m = bm + lr;
    const int n = bn + lr;

    float acc[4][4] = {};
    float ar[4], wr[4];

    auto loadA = [&](int k0, float r[4]) {
        int k = k0 + lc;
        if (AMODE == 0) {
            if (m < M && k < K) *(float4*)r = *(const float4*)&A[(size_t)m * lda + k];
            else { r[0] = r[1] = r[2] = r[3] = 0.f; }
        } else if (AMODE == 1) {
            int b = m >> 8, t = m & 255;
            int gh = t >> 3, gw = t & 7;
            int p1 = k >> 4, p2 = k & 15;
            *(float4*)r = *(const float4*)&gA[(size_t)b * 65536 + gh * 2048 + p1 * 128 + gw * 16 + p2];
        } else {  // AMODE 2: flip-add
            if (m < M) {
                int b = m / LF, l = m - b * LF;
                float4 v1 = *(const float4*)&A[(size_t)m * lda + k];
                float4 v2 = *(const float4*)&A2[(size_t)(b * LF + (LF - 1 - l)) * lda + k];
                r[0] = v1.x + v2.x; r[1] = v1.y + v2.y;
                r[2] = v1.z + v2.z; r[3] = v1.w + v2.w;
            } else { r[0] = r[1] = r[2] = r[3] = 0.f; }
        }
    };
    auto loadW = [&](int k0, float r[4]) {
        int k = k0 + lc;
        if (n < N && k < K) *(float4*)r = *(const float4*)&W[(size_t)n * K + k];
        else { r[0] = r[1] = r[2] = r[3] = 0.f; }
    };

    loadA(0, ar);
    loadW(0, wr);

    for (int k0 = 0; k0 < K; k0 += 16) {
        #pragma unroll
        for (int u = 0; u < 4; ++u) {
            As[lc + u][lr] = ar[u];
            Ws[lc + u][lr] = wr[u];
        }
        __syncthreads();
        if (k0 + 16 < K) {           // prefetch next tile during compute
            loadA(k0 + 16, ar);
            loadW(k0 + 16, wr);
        }
        #pragma unroll
        for (int kk = 0; kk < 16; ++kk) {
            float a[4], w[4];
            *(float4*)a = *(const float4*)&As[kk][ty * 4];
            *(float4*)w = *(const float4*)&Ws[kk][tx * 4];
            #pragma unroll
            for (int i = 0; i < 4; ++i)
                #pragma unroll
                for (int j = 0; j < 4; ++j)
                    acc[i][j] += a[i] * w[j];
        }
        __syncthreads();
    }

    #pragma unroll
    for (int i = 0; i < 4; ++i) {
        int mm = bm + ty * 4 + i;
        if (mm >= M) continue;
        #pragma unroll
        for (int j = 0; j < 4; ++j) {
            int nn = bn + tx * 4 + j;
            if (nn >= N) continue;
            float v = acc[i][j];
            if (SMODE == 0) {
                if (bias) v += bias[nn];
                Cout[(size_t)mm * N + nn] = v;
            } else if (SMODE == 1) {
                v += bias[nn];
                Cout[(size_t)mm * N + nn] = softplusf(v);
            } else if (SMODE == 2) {
                Cout[(size_t)mm * N + nn] += v;
            } else {  // SMODE 3: patchify store
                int b = mm >> 8, t = mm & 255;
                int l = (t < POSROW) ? t : t + 1;
                v += bias[nn] + pos[(size_t)l * DMODEL + nn];
                Cout[(size_t)(b * LF + l) * DMODEL + nn] = v;
            }
        }
    }
}

// cls row: residual[b, 128, :] = cls + pos[128]
__global__ void cls_k(const float* __restrict__ cls, const float* __restrict__ pos,
                      float* __restrict__ residual) {
    int b = blockIdx.x, t = threadIdx.x;
    residual[(size_t)(b * LF + POSROW) * DMODEL + t] =
        cls[t] + pos[(size_t)POSROW * DMODEL + t];
}

// row-wise layernorm over 384, 128 threads x 3 elems
__global__ __launch_bounds__(128) void ln_k(const float* __restrict__ X,
                                            const float* __restrict__ w,
                                            const float* __restrict__ b,
                                            float* __restrict__ Y) {
    int r = blockIdx.x;
    const float* x = X + (size_t)r * DMODEL;
    int t = threadIdx.x;
    float v0 = x[t], v1 = x[t + 128], v2 = x[t + 256];
    float s = v0 + v1 + v2;
    float sq = v0 * v0 + v1 * v1 + v2 * v2;
    #pragma unroll
    for (int o = 32; o > 0; o >>= 1) {
        s += __shfl_down(s, o);
        sq += __shfl_down(sq, o);
    }
    __shared__ float ls[2], lq[2];
    if ((t & 63) == 0) { ls[t >> 6] = s; lq[t >> 6] = sq; }
    __syncthreads();
    float S = ls[0] + ls[1], Q = lq[0] + lq[1];
    float mean = S * (1.f / 384.f);
    float var = Q * (1.f / 384.f) - mean * mean;
    float rs = rsqrtf(var + 1e-5f);
    float* y = Y + (size_t)r * DMODEL;
    y[t]       = (v0 - mean) * rs * w[t]       + b[t];
    y[t + 128] = (v1 - mean) * rs * w[t + 128] + b[t + 128];
    y[t + 256] = (v2 - mean) * rs * w[t + 256] + b[t + 256];
}

// fused fwd+bwd causal depthwise conv (K=4) + SiLU
__global__ __launch_bounds__(256) void conv_k(
    const float* __restrict__ xz,
    const float* __restrict__ cw, const float* __restrict__ cb,
    const float* __restrict__ cwb, const float* __restrict__ cbb,
    float* __restrict__ xcf, float* __restrict__ xcb) {
    int g = blockIdx.x * 256 + threadIdx.x;
    if (g >= BB * LF * DIN) return;
    int d = g % DIN;
    int rm = g / DIN;
    int b = rm / LF, l = rm - b * LF;
    const float* xb = xz + (size_t)b * LF * (2 * DIN);
    float wf[4], wb[4];
    #pragma unroll
    for (int k = 0; k < 4; ++k) {
        wf[k] = cw[d * 4 + k];
        wb[k] = cwb[d * 4 + k];
    }
    float af = cb[d], ab = cbb[d];
    #pragma unroll
    for (int k = 0; k < 4; ++k) {
        int li = l - 3 + k;
        if (li >= 0) {
            af += xb[(size_t)li * (2 * DIN) + d] * wf[k];
            ab += xb[(size_t)(LF - 1 - li) * (2 * DIN) + d] * wb[k];
        }
    }
    xcf[(size_t)rm * DIN + d] = siluf(af);
    xcb[(size_t)rm * DIN + d] = siluf(ab);
}

// selective scan, both branches via blockIdx.z; 256 channels/block.
// Fully-unrolled 8-step chunks (all per-chunk state in VGPRs, no scratch),
// register double-buffer: next chunk's 25 loads issue BEFORE computing the
// current chunk, so the end-of-chunk barrier's vmcnt drain is nearly free.
#define SCH 8
__global__ __launch_bounds__(256) void scan_k(
    const float* __restrict__ xcf, const float* __restrict__ dtf,
    const float* __restrict__ xdbf,
    const float* __restrict__ xcb, const float* __restrict__ dtb,
    const float* __restrict__ xdbb,
    const float* __restrict__ xz,
    const float* __restrict__ alf, const float* __restrict__ dpf,
    const float* __restrict__ alb, const float* __restrict__ dpb,
    float* __restrict__ yf, float* __restrict__ yb) {
    const int br = blockIdx.z;
    const int b = blockIdx.y;
    const int t = threadIdx.x;
    const int d = blockIdx.x * 256 + t;
    const float* xc  = br ? xcb  : xcf;
    const float* dt  = br ? dtb  : dtf;
    const float* xdb = br ? xdbb : xdbf;
    const float* Al  = br ? alb  : alf;
    const float* Dpp = br ? dpb  : dpf;
    float* yo        = br ? yb   : yf;

    float An[NST], h[NST];
    #pragma unroll
    for (int n = 0; n < NST; ++n) {
        An[n] = -__expf(Al[(size_t)d * NST + n]);
        h[n] = 0.f;
    }
    float Dv = Dpp[d];

    __shared__ float sBC[2][SCH][32];
    const int ss = t >> 5;          // 0..7: step this thread stages
    const int sj = t & 31;          // 0..31: B/C element

    float dc[SCH], xv[SCH], zc[SCH];
    // prefetch chunk 0 + stage its B/C
    #pragma unroll
    for (int s = 0; s < SCH; ++s) {
        int row = b * LF + s;
        dc[s] = dt[(size_t)row * DIN + d];
        xv[s] = xc[(size_t)row * DIN + d];
        int zl = br ? (LF - 1 - s) : s;
        zc[s] = xz[(size_t)(b * LF + zl) * (2 * DIN) + DIN + d];
    }
    sBC[0][ss][sj] = xdb[(size_t)(b * LF + ss) * XDB + DTR + sj];
    __syncthreads();

    for (int c0 = 0; c0 < LF; c0 += SCH) {
        const int buf = (c0 >> 3) & 1;
        const bool hasnext = (c0 + SCH) < LF;
        float dn[SCH], xn[SCH], zn[SCH], bcn = 0.f;
        // issue next chunk's loads now; they complete during compute
        if (hasnext) {
            #pragma unroll
            for (int s = 0; s < SCH; ++s) {
                int l = c0 + SCH + s;
                if (l < LF) {
                    int row = b * LF + l;
                    dn[s] = dt[(size_t)row * DIN + d];
                    xn[s] = xc[(size_t)row * DIN + d];
                    int zl = br ? (LF - 1 - l) : l;
                    zn[s] = xz[(size_t)(b * LF + zl) * (2 * DIN) + DIN + d];
                }
            }
            int lb = c0 + SCH + ss;
            if (lb < LF) bcn = xdb[(size_t)(b * LF + lb) * XDB + DTR + sj];
        }
        // compute current chunk (fully unrolled -> arrays stay in VGPRs)
        #pragma unroll
        for (int s = 0; s < SCH; ++s) {
            if (c0 + s < LF) {
                float dtv = dc[s];
                float dtx = dtv * xv[s];
                float acc = 0.f;
                #pragma unroll
                for (int n = 0; n < NST; ++n) {
                    float dA = __expf(dtv * An[n]);
                    h[n] = dA * h[n] + dtx * sBC[buf][s][n];
                    acc += h[n] * sBC[buf][s][NST + n];
                }
                yo[(size_t)(b * LF + c0 + s) * DIN + d] = (acc + xv[s] * Dv) * siluf(zc[s]);
            }
        }
        // stage next B/C and rotate
        if (hasnext) {
            if (c0 + SCH + ss < LF) sBC[buf ^ 1][ss][sj] = bcn;
            __syncthreads();
            #pragma unroll
            for (int s = 0; s < SCH; ++s) { dc[s] = dn[s]; xv[s] = xn[s]; zc[s] = zn[s]; }
        }
    }
}

// final LN(row POS) + command MLP + add -> f32 out
__global__ __launch_bounds__(384) void final_k(
    const float* __restrict__ residual,
    const float* __restrict__ lnw, const float* __restrict__ lnb,
    const float* __restrict__ sv, const float* __restrict__ act,
    const float* __restrict__ cw1, const float* __restrict__ cb1,
    const float* __restrict__ cw2, const float* __restrict__ cb2,
    float* __restrict__ out) {
    int b = blockIdx.x, t = threadIdx.x;
    const float* x = residual + (size_t)(b * LF + POSROW) * DMODEL;
    float v = x[t];
    float s = v, sq = v * v;
    #pragma unroll
    for (int o = 32; o > 0; o >>= 1) {
        s += __shfl_down(s, o);
        sq += __shfl_down(sq, o);
    }
    __shared__ float ls[6], lq[6], hid[DMODEL], cmdin[20];
    if ((t & 63) == 0) { ls[t >> 6] = s; lq[t >> 6] = sq; }
    if (t < 20) cmdin[t] = (t < 16) ? sv[b * 16 + t] : act[b * 4 + t - 16];
    __syncthreads();
    float S = 0.f, Q = 0.f;
    #pragma unroll
    for (int w = 0; w < 6; ++w) { S += ls[w]; Q += lq[w]; }
    float mean = S * (1.f / 384.f);
    float var = Q * (1.f / 384.f) - mean * mean;
    float rs = rsqrtf(var + 1e-5f);
    float vis = (v - mean) * rs * lnw[t] + lnb[t];
    float a1 = cb1[t];
    #pragma unroll
    for (int k = 0; k < 20; ++k) a1 += cmdin[k] * cw1[t * 20 + k];
    hid[t] = fmaxf(a1, 0.f);
    __syncthreads();
    float a2 = cb2[t];
    for (int k = 0; k < DMODEL; ++k) a2 += hid[k] * cw2[t * DMODEL + k];
    out[b * DMODEL + t] = vis + a2;
}

extern "C" void kernel_launch(void* const* d_in, const int* in_sizes, int n_in,
                              void* d_out, int out_size, void* d_ws, size_t ws_size,
                              hipStream_t stream) {
    const float* depth_seq = (const float*)d_in[0];
    const float* state_vec = (const float*)d_in[1];
    const float* action    = (const float*)d_in[2];
    const float* patch_w   = (const float*)d_in[3];
    const float* patch_b   = (const float*)d_in[4];
    const float* cls_token = (const float*)d_in[5];
    const float* pos_embed = (const float*)d_in[6];
    const float* ln_w      = (const float*)d_in[7];
    const float* ln_b      = (const float*)d_in[8];
    const float* in_proj_w = (const float*)d_in[9];
    const float* conv_w    = (const float*)d_in[10];
    const float* conv_b    = (const float*)d_in[11];
    const float* conv_wb   = (const float*)d_in[12];
    const float* conv_bb   = (const float*)d_in[13];
    const float* xproj_w   = (const float*)d_in[14];
    const float* xproj_wb  = (const float*)d_in[15];
    const float* dtproj_w  = (const float*)d_in[16];
    const float* dtproj_b  = (const float*)d_in[17];
    const float* dtproj_wb = (const float*)d_in[18];
    const float* dtproj_bb = (const float*)d_in[19];
    const float* A_log     = (const float*)d_in[20];
    const float* A_logb    = (const float*)d_in[21];
    const float* Dp        = (const float*)d_in[22];
    const float* Dpb       = (const float*)d_in[23];
    const float* out_w     = (const float*)d_in[24];
    const float* lnf_w     = (const float*)d_in[25];
    const float* lnf_b     = (const float*)d_in[26];
    const float* cw1       = (const float*)d_in[27];
    const float* cb1       = (const float*)d_in[28];
    const float* cw2       = (const float*)d_in[29];
    const float* cb2       = (const float*)d_in[30];

    const int M = BB * LF;  // 1028
    float* ws = (float*)d_ws;
    size_t o = 0;
    float* residual = ws + o; o += (size_t)M * DMODEL;
    float* h_ln     = ws + o; o += (size_t)M * DMODEL;
    float* xz       = ws + o; o += (size_t)M * 2 * DIN;
    float* xcf      = ws + o; o += (size_t)M * DIN;
    float* xcb      = ws + o; o += (size_t)M * DIN;
    float* xdbf     = ws + o; o += (size_t)M * XDB;
    float* xdbb     = ws + o; o += (size_t)M * XDB;
    float* dtf      = ws + o; o += (size_t)M * DIN;
    float* dtb      = ws + o; o += (size_t)M * DIN;
    float* yfb      = ws + o; o += (size_t)M * DIN;
    float* ybb      = ws + o; o += (size_t)M * DIN;
    (void)ws_size; (void)in_sizes; (void)n_in; (void)out_size;

    // patchify -> residual (with bias + pos, cls gap)
    gemm_k<1, 3><<<dim3(16, 6), 256, 0, stream>>>(
        nullptr, 0, patch_w, patch_b, residual, 1024, DMODEL, 256,
        depth_seq, nullptr, pos_embed);
    cls_k<<<BB, DMODEL, 0, stream>>>(cls_token, pos_embed, residual);

    for (int i = 0; i < 4; ++i) {
        ln_k<<<M, 128, 0, stream>>>(residual, ln_w + (size_t)i * DMODEL,
                                    ln_b + (size_t)i * DMODEL, h_ln);
        // in_proj: (1028 x 384) @ (384 x 1536)^T
        gemm_k<0, 0><<<dim3(17, 24), 256, 0, stream>>>(
            h_ln, DMODEL, in_proj_w + (size_t)i * 2 * DIN * DMODEL, nullptr,
            xz, M, 2 * DIN, DMODEL, nullptr, nullptr, nullptr);
        conv_k<<<(BB * LF * DIN) / 256, 256, 0, stream>>>(
            xz, conv_w + (size_t)i * DIN * 4, conv_b + (size_t)i * DIN,
            conv_wb + (size_t)i * DIN * 4, conv_bb + (size_t)i * DIN, xcf, xcb);
        // x_proj: (1028 x 768) @ (768 x 56)^T
        gemm_k<0, 0><<<dim3(17, 1), 256, 0, stream>>>(
            xcf, DIN, xproj_w + (size_t)i * XDB * DIN, nullptr,
            xdbf, M, XDB, DIN, nullptr, nullptr, nullptr);
        gemm_k<0, 0><<<dim3(17, 1), 256, 0, stream>>>(
            xcb, DIN, xproj_wb + (size_t)i * XDB * DIN, nullptr,
            xdbb, M, XDB, DIN, nullptr, nullptr, nullptr);
        // dt: (1028 x 24) @ (24 x 768)^T + softplus
        gemm_k<0, 1><<<dim3(17, 12), 256, 0, stream>>>(
            xdbf, XDB, dtproj_w + (size_t)i * DIN * DTR, dtproj_b + (size_t)i * DIN,
            dtf, M, DIN, DTR, nullptr, nullptr, nullptr);
        gemm_k<0, 1><<<dim3(17, 12), 256, 0, stream>>>(
            xdbb, XDB, dtproj_wb + (size_t)i * DIN * DTR, dtproj_bb + (size_t)i * DIN,
            dtb, M, DIN, DTR, nullptr, nullptr, nullptr);
        // selective scan, both branches
        scan_k<<<dim3(3, BB, 2), 256, 0, stream>>>(
            xcf, dtf, xdbf, xcb, dtb, xdbb, xz,
            A_log + (size_t)i * DIN * NST, Dp + (size_t)i * DIN,
            A_logb + (size_t)i * DIN * NST, Dpb + (size_t)i * DIN, yfb, ybb);
        // out_proj with fused flip-add, residual +=
        gemm_k<2, 2><<<dim3(17, 6), 256, 0, stream>>>(
            yfb, DIN, out_w + (size_t)i * DMODEL * DIN, nullptr,
            residual, M, DMODEL, DIN, nullptr, ybb, nullptr);
    }

    final_k<<<BB, DMODEL, 0, stream>>>(
        residual, lnf_w, lnf_b, state_vec, action, cw1, cb1, cw2, cb2,
        (float*)d_out);
}

// Round 6
// 845.158 us; speedup vs baseline: 3.2846x; 1.5788x over previous
//
#include <hip/hip_runtime.h>
#include <hip/hip_bf16.h>
#include <math.h>

#define BB 4
#define LF 257      // NTOK+1
#define DMODEL 384
#define DIN 768
#define NST 16
#define DTR 24
#define XDB 56      // DTR + 2*N
#define POSROW 128
#define CL 16       // scan chunk length
#define NC 17       // ceil(LF/CL)

__device__ __forceinline__ float siluf(float v) { return v / (1.f + __expf(-v)); }
__device__ __forceinline__ float softplusf(float v) {
    return (v > 20.f) ? v : log1pf(__expf(v));
}

// ---------------------------------------------------------------------------
// Plain-A GEMM core: C[m,n] = act( sum_k A[m,k]*W[n,k] + bias[n] )
// LDS tiles transposed [k][m] stride 68, float4 staging, reg double-buffer.
// SMODE: 0 plain(+bias), 1 softplus(+bias)
// ---------------------------------------------------------------------------
template<int SMODE>
__device__ __forceinline__ void gemm_core(
    const float* __restrict__ A, int lda,
    const float* __restrict__ W,
    const float* __restrict__ bias,
    float* __restrict__ Cout, int M, int N, int K)
{
    __shared__ float As[16][68];
    __shared__ float Ws[16][68];
    const int tid = threadIdx.x;
    const int tx = tid & 15, ty = tid >> 4;
    const int bm = blockIdx.x * 64, bn = blockIdx.y * 64;
    const int lr = tid >> 2;
    const int lc = (tid & 3) * 4;
    const int m = bm + lr;
    const int n = bn + lr;

    float acc[4][4] = {};
    float ar[4], wr[4];

    auto loadA = [&](int k0, float r[4]) {
        int k = k0 + lc;
        if (m < M && k < K) *(float4*)r = *(const float4*)&A[(size_t)m * lda + k];
        else { r[0] = r[1] = r[2] = r[3] = 0.f; }
    };
    auto loadW = [&](int k0, float r[4]) {
        int k = k0 + lc;
        if (n < N && k < K) *(float4*)r = *(const float4*)&W[(size_t)n * K + k];
        else { r[0] = r[1] = r[2] = r[3] = 0.f; }
    };

    loadA(0, ar);
    loadW(0, wr);

    for (int k0 = 0; k0 < K; k0 += 16) {
        #pragma unroll
        for (int u = 0; u < 4; ++u) {
            As[lc + u][lr] = ar[u];
            Ws[lc + u][lr] = wr[u];
        }
        __syncthreads();
        if (k0 + 16 < K) { loadA(k0 + 16, ar); loadW(k0 + 16, wr); }
        #pragma unroll
        for (int kk = 0; kk < 16; ++kk) {
            float a[4], w[4];
            *(float4*)a = *(const float4*)&As[kk][ty * 4];
            *(float4*)w = *(const float4*)&Ws[kk][tx * 4];
            #pragma unroll
            for (int i = 0; i < 4; ++i)
                #pragma unroll
                for (int j = 0; j < 4; ++j)
                    acc[i][j] += a[i] * w[j];
        }
        __syncthreads();
    }

    #pragma unroll
    for (int i = 0; i < 4; ++i) {
        int mm = bm + ty * 4 + i;
        if (mm >= M) continue;
        #pragma unroll
        for (int j = 0; j < 4; ++j) {
            int nn = bn + tx * 4 + j;
            if (nn >= N) continue;
            float v = acc[i][j];
            if (SMODE == 0) {
                if (bias) v += bias[nn];
                Cout[(size_t)mm * N + nn] = v;
            } else {
                v += bias[nn];
                Cout[(size_t)mm * N + nn] = softplusf(v);
            }
        }
    }
}

// dual-dispatch plain GEMM: blockIdx.z selects operand set (fwd/bwd branch)
template<int SMODE>
__global__ __launch_bounds__(256) void gemm_pair_k(
    const float* __restrict__ A0, const float* __restrict__ W0,
    const float* __restrict__ b0, float* __restrict__ C0,
    const float* __restrict__ A1, const float* __restrict__ W1,
    const float* __restrict__ b1, float* __restrict__ C1,
    int lda, int M, int N, int K)
{
    if (blockIdx.z == 0) gemm_core<SMODE>(A0, lda, W0, b0, C0, M, N, K);
    else                 gemm_core<SMODE>(A1, lda, W1, b1, C1, M, N, K);
}

// ---------------------------------------------------------------------------
// Special GEMMs (patchify gather / flip-add accumulate), same tile scheme.
// AMODE: 1 patch gather, 2 flip-add.  SMODE: 2 accumulate, 3 patchify store.
// ---------------------------------------------------------------------------
template<int AMODE, int SMODE>
__global__ __launch_bounds__(256) void gemm_k(
    const float* __restrict__ A, int lda,
    const float* __restrict__ W,
    const float* __restrict__ bias,
    float* __restrict__ Cout,
    int M, int N, int K,
    const float* __restrict__ gA,
    const float* __restrict__ A2,
    const float* __restrict__ pos)
{
    __shared__ float As[16][68];
    __shared__ float Ws[16][68];
    const int tid = threadIdx.x;
    const int tx = tid & 15, ty = tid >> 4;
    const int bm = blockIdx.x * 64, bn = blockIdx.y * 64;
    const int lr = tid >> 2;
    const int lc = (tid & 3) * 4;
    const int m = bm + lr;
    const int n = bn + lr;

    float acc[4][4] = {};
    float ar[4], wr[4];

    auto loadA = [&](int k0, float r[4]) {
        int k = k0 + lc;
        if (AMODE == 1) {
            int b = m >> 8, t = m & 255;
            int gh = t >> 3, gw = t & 7;
            int p1 = k >> 4, p2 = k & 15;
            *(float4*)r = *(const float4*)&gA[(size_t)b * 65536 + gh * 2048 + p1 * 128 + gw * 16 + p2];
        } else {  // AMODE 2: flip-add
            if (m < M) {
                int b = m / LF, l = m - b * LF;
                float4 v1 = *(const float4*)&A[(size_t)m * lda + k];
                float4 v2 = *(const float4*)&A2[(size_t)(b * LF + (LF - 1 - l)) * lda + k];
                r[0] = v1.x + v2.x; r[1] = v1.y + v2.y;
                r[2] = v1.z + v2.z; r[3] = v1.w + v2.w;
            } else { r[0] = r[1] = r[2] = r[3] = 0.f; }
        }
    };
    auto loadW = [&](int k0, float r[4]) {
        int k = k0 + lc;
        if (n < N && k < K) *(float4*)r = *(const float4*)&W[(size_t)n * K + k];
        else { r[0] = r[1] = r[2] = r[3] = 0.f; }
    };

    loadA(0, ar);
    loadW(0, wr);

    for (int k0 = 0; k0 < K; k0 += 16) {
        #pragma unroll
        for (int u = 0; u < 4; ++u) {
            As[lc + u][lr] = ar[u];
            Ws[lc + u][lr] = wr[u];
        }
        __syncthreads();
        if (k0 + 16 < K) { loadA(k0 + 16, ar); loadW(k0 + 16, wr); }
        #pragma unroll
        for (int kk = 0; kk < 16; ++kk) {
            float a[4], w[4];
            *(float4*)a = *(const float4*)&As[kk][ty * 4];
            *(float4*)w = *(const float4*)&Ws[kk][tx * 4];
            #pragma unroll
            for (int i = 0; i < 4; ++i)
                #pragma unroll
                for (int j = 0; j < 4; ++j)
                    acc[i][j] += a[i] * w[j];
        }
        __syncthreads();
    }

    #pragma unroll
    for (int i = 0; i < 4; ++i) {
        int mm = bm + ty * 4 + i;
        if (mm >= M) continue;
        #pragma unroll
        for (int j = 0; j < 4; ++j) {
            int nn = bn + tx * 4 + j;
            if (nn >= N) continue;
            float v = acc[i][j];
            if (SMODE == 2) {
                Cout[(size_t)mm * N + nn] += v;
            } else {  // SMODE 3: patchify store
                int b = mm >> 8, t = mm & 255;
                int l = (t < POSROW) ? t : t + 1;
                v += bias[nn] + pos[(size_t)l * DMODEL + nn];
                Cout[(size_t)(b * LF + l) * DMODEL + nn] = v;
            }
        }
    }
}

// cls row: residual[b, 128, :] = cls + pos[128]
__global__ void cls_k(const float* __restrict__ cls, const float* __restrict__ pos,
                      float* __restrict__ residual) {
    int b = blockIdx.x, t = threadIdx.x;
    residual[(size_t)(b * LF + POSROW) * DMODEL + t] =
        cls[t] + pos[(size_t)POSROW * DMODEL + t];
}

// row-wise layernorm over 384
__global__ __launch_bounds__(128) void ln_k(const float* __restrict__ X,
                                            const float* __restrict__ w,
                                            const float* __restrict__ b,
                                            float* __restrict__ Y) {
    int r = blockIdx.x;
    const float* x = X + (size_t)r * DMODEL;
    int t = threadIdx.x;
    float v0 = x[t], v1 = x[t + 128], v2 = x[t + 256];
    float s = v0 + v1 + v2;
    float sq = v0 * v0 + v1 * v1 + v2 * v2;
    #pragma unroll
    for (int o = 32; o > 0; o >>= 1) {
        s += __shfl_down(s, o);
        sq += __shfl_down(sq, o);
    }
    __shared__ float ls[2], lq[2];
    if ((t & 63) == 0) { ls[t >> 6] = s; lq[t >> 6] = sq; }
    __syncthreads();
    float S = ls[0] + ls[1], Q = lq[0] + lq[1];
    float mean = S * (1.f / 384.f);
    float var = Q * (1.f / 384.f) - mean * mean;
    float rs = rsqrtf(var + 1e-5f);
    float* y = Y + (size_t)r * DMODEL;
    y[t]       = (v0 - mean) * rs * w[t]       + b[t];
    y[t + 128] = (v1 - mean) * rs * w[t + 128] + b[t + 128];
    y[t + 256] = (v2 - mean) * rs * w[t + 256] + b[t + 256];
}

// fused fwd+bwd causal depthwise conv (K=4) + SiLU
__global__ __launch_bounds__(256) void conv_k(
    const float* __restrict__ xz,
    const float* __restrict__ cw, const float* __restrict__ cb,
    const float* __restrict__ cwb, const float* __restrict__ cbb,
    float* __restrict__ xcf, float* __restrict__ xcb) {
    int g = blockIdx.x * 256 + threadIdx.x;
    if (g >= BB * LF * DIN) return;
    int d = g % DIN;
    int rm = g / DIN;
    int b = rm / LF, l = rm - b * LF;
    const float* xb = xz + (size_t)b * LF * (2 * DIN);
    float wf[4], wb[4];
    #pragma unroll
    for (int k = 0; k < 4; ++k) {
        wf[k] = cw[d * 4 + k];
        wb[k] = cwb[d * 4 + k];
    }
    float af = cb[d], ab = cbb[d];
    #pragma unroll
    for (int k = 0; k < 4; ++k) {
        int li = l - 3 + k;
        if (li >= 0) {
            af += xb[(size_t)li * (2 * DIN) + d] * wf[k];
            ab += xb[(size_t)(LF - 1 - li) * (2 * DIN) + d] * wb[k];
        }
    }
    xcf[(size_t)rm * DIN + d] = siluf(af);
    xcb[(size_t)rm * DIN + d] = siluf(ab);
}

// ---------------------------------------------------------------------------
// Chunked associative scan. h[l] = exp(dt*An)h[l-1] + dt*xc*B[l] is linear;
// chunk transition = (exp(An*sum_dt), h_partial). Pass A: per-chunk partials
// (17x parallelism). Pass C: combine prefix (<=16 cheap steps) then full
// recurrence + y output.  Grid (3, BB*2, NC), 256 thr.
// ---------------------------------------------------------------------------
__global__ __launch_bounds__(256) void scanA_k(
    const float* __restrict__ xcf, const float* __restrict__ dtf,
    const float* __restrict__ xdbf,
    const float* __restrict__ xcb, const float* __restrict__ dtb,
    const float* __restrict__ xdbb,
    const float* __restrict__ alf, const float* __restrict__ alb,
    float* __restrict__ hpart, float* __restrict__ sumd) {
    const int t = threadIdx.x;
    const int y = blockIdx.y;            // b*2+br
    const int b = y >> 1, br = y & 1;
    const int c = blockIdx.z;
    const int d = blockIdx.x * 256 + t;
    const float* xc  = br ? xcb  : xcf;
    const float* dt  = br ? dtb  : dtf;
    const float* xdb = br ? xdbb : xdbf;
    const float* Al  = br ? alb  : alf;

    float An[NST];
    #pragma unroll
    for (int n = 0; n < NST; ++n) An[n] = -__expf(Al[(size_t)d * NST + n]);

    __shared__ float sB[CL][NST];
    {
        int s0 = t >> 4, j0 = t & 15;
        int l0 = c * CL + s0;
        sB[s0][j0] = (l0 < LF) ? xdb[(size_t)(b * LF + l0) * XDB + DTR + j0] : 0.f;
    }
    __syncthreads();

    float h[NST] = {};
    float sdt = 0.f;
    #pragma unroll
    for (int s = 0; s < CL; ++s) {
        int l = c * CL + s;
        if (l < LF) {
            int row = b * LF + l;
            float dtv = dt[(size_t)row * DIN + d];
            float xcv = xc[(size_t)row * DIN + d];
            sdt += dtv;
            float dtx = dtv * xcv;
            #pragma unroll
            for (int n = 0; n < NST; ++n)
                h[n] = __expf(dtv * An[n]) * h[n] + dtx * sB[s][n];
        }
    }
    size_t base = (size_t)(c * 8 + y) * NST;
    #pragma unroll
    for (int n = 0; n < NST; ++n) hpart[(base + n) * DIN + d] = h[n];
    sumd[(size_t)(c * 8 + y) * DIN + d] = sdt;
}

__global__ __launch_bounds__(256) void scanC_k(
    const float* __restrict__ xcf, const float* __restrict__ dtf,
    const float* __restrict__ xdbf,
    const float* __restrict__ xcb, const float* __restrict__ dtb,
    const float* __restrict__ xdbb,
    const float* __restrict__ xz,
    const float* __restrict__ alf, const float* __restrict__ dpf,
    const float* __restrict__ alb, const float* __restrict__ dpb,
    const float* __restrict__ hpart, const float* __restrict__ sumd,
    float* __restrict__ yf, float* __restrict__ yb) {
    const int t = threadIdx.x;
    const int y = blockIdx.y;
    const int b = y >> 1, br = y & 1;
    const int c = blockIdx.z;
    const int d = blockIdx.x * 256 + t;
    const float* xc  = br ? xcb  : xcf;
    const float* dt  = br ? dtb  : dtf;
    const float* xdb = br ? xdbb : xdbf;
    const float* Al  = br ? alb  : alf;
    const float* Dpp = br ? dpb  : dpf;
    float* yo        = br ? yb   : yf;

    float An[NST];
    #pragma unroll
    for (int n = 0; n < NST; ++n) An[n] = -__expf(Al[(size_t)d * NST + n]);
    float Dv = Dpp[d];

    __shared__ float sB[CL][NST];
    __shared__ float sC[CL][NST];
    {
        int s0 = t >> 4, j0 = t & 15;
        int l0 = c * CL + s0;
        size_t rb = (size_t)(b * LF + l0) * XDB + DTR;
        sB[s0][j0] = (l0 < LF) ? xdb[rb + j0] : 0.f;
        sC[s0][j0] = (l0 < LF) ? xdb[rb + NST + j0] : 0.f;
    }
    __syncthreads();

    // combine prefix: h_in for this chunk
    float h[NST] = {};
    for (int j = 0; j < c; ++j) {
        float sd = sumd[(size_t)(j * 8 + y) * DIN + d];
        size_t base = (size_t)(j * 8 + y) * NST;
        #pragma unroll
        for (int n = 0; n < NST; ++n)
            h[n] = __expf(An[n] * sd) * h[n] + hpart[(base + n) * DIN + d];
    }

    #pragma unroll
    for (int s = 0; s < CL; ++s) {
        int l = c * CL + s;
        if (l < LF) {
            int row = b * LF + l;
            float dtv = dt[(size_t)row * DIN + d];
            float xcv = xc[(size_t)row * DIN + d];
            int zl = br ? (LF - 1 - l) : l;
            float zv = xz[(size_t)(b * LF + zl) * (2 * DIN) + DIN + d];
            float dtx = dtv * xcv;
            float acc = 0.f;
            #pragma unroll
            for (int n = 0; n < NST; ++n) {
                h[n] = __expf(dtv * An[n]) * h[n] + dtx * sB[s][n];
                acc += h[n] * sC[s][n];
            }
            yo[(size_t)row * DIN + d] = (acc + xcv * Dv) * siluf(zv);
        }
    }
}

// final LN(row POS) + command MLP + add -> f32 out
__global__ __launch_bounds__(384) void final_k(
    const float* __restrict__ residual,
    const float* __restrict__ lnw, const float* __restrict__ lnb,
    const float* __restrict__ sv, const float* __restrict__ act,
    const float* __restrict__ cw1, const float* __restrict__ cb1,
    const float* __restrict__ cw2, const float* __restrict__ cb2,
    float* __restrict__ out) {
    int b = blockIdx.x, t = threadIdx.x;
    const float* x = residual + (size_t)(b * LF + POSROW) * DMODEL;
    float v = x[t];
    float s = v, sq = v * v;
    #pragma unroll
    for (int o = 32; o > 0; o >>= 1) {
        s += __shfl_down(s, o);
        sq += __shfl_down(sq, o);
    }
    __shared__ float ls[6], lq[6], hid[DMODEL], cmdin[20];
    if ((t & 63) == 0) { ls[t >> 6] = s; lq[t >> 6] = sq; }
    if (t < 20) cmdin[t] = (t < 16) ? sv[b * 16 + t] : act[b * 4 + t - 16];
    __syncthreads();
    float S = 0.f, Q = 0.f;
    #pragma unroll
    for (int w = 0; w < 6; ++w) { S += ls[w]; Q += lq[w]; }
    float mean = S * (1.f / 384.f);
    float var = Q * (1.f / 384.f) - mean * mean;
    float rs = rsqrtf(var + 1e-5f);
    float vis = (v - mean) * rs * lnw[t] + lnb[t];
    float a1 = cb1[t];
    #pragma unroll
    for (int k = 0; k < 20; ++k) a1 += cmdin[k] * cw1[t * 20 + k];
    hid[t] = fmaxf(a1, 0.f);
    __syncthreads();
    float a2 = cb2[t];
    for (int k = 0; k < DMODEL; ++k) a2 += hid[k] * cw2[t * DMODEL + k];
    out[b * DMODEL + t] = vis + a2;
}

extern "C" void kernel_launch(void* const* d_in, const int* in_sizes, int n_in,
                              void* d_out, int out_size, void* d_ws, size_t ws_size,
                              hipStream_t stream) {
    const float* depth_seq = (const float*)d_in[0];
    const float* state_vec = (const float*)d_in[1];
    const float* action    = (const float*)d_in[2];
    const float* patch_w   = (const float*)d_in[3];
    const float* patch_b   = (const float*)d_in[4];
    const float* cls_token = (const float*)d_in[5];
    const float* pos_embed = (const float*)d_in[6];
    const float* ln_w      = (const float*)d_in[7];
    const float* ln_b      = (const float*)d_in[8];
    const float* in_proj_w = (const float*)d_in[9];
    const float* conv_w    = (const float*)d_in[10];
    const float* conv_b    = (const float*)d_in[11];
    const float* conv_wb   = (const float*)d_in[12];
    const float* conv_bb   = (const float*)d_in[13];
    const float* xproj_w   = (const float*)d_in[14];
    const float* xproj_wb  = (const float*)d_in[15];
    const float* dtproj_w  = (const float*)d_in[16];
    const float* dtproj_b  = (const float*)d_in[17];
    const float* dtproj_wb = (const float*)d_in[18];
    const float* dtproj_bb = (const float*)d_in[19];
    const float* A_log     = (const float*)d_in[20];
    const float* A_logb    = (const float*)d_in[21];
    const float* Dp        = (const float*)d_in[22];
    const float* Dpb       = (const float*)d_in[23];
    const float* out_w     = (const float*)d_in[24];
    const float* lnf_w     = (const float*)d_in[25];
    const float* lnf_b     = (const float*)d_in[26];
    const float* cw1       = (const float*)d_in[27];
    const float* cb1       = (const float*)d_in[28];
    const float* cw2       = (const float*)d_in[29];
    const float* cb2       = (const float*)d_in[30];

    const int M = BB * LF;  // 1028
    float* ws = (float*)d_ws;
    size_t o = 0;
    float* residual = ws + o; o += (size_t)M * DMODEL;
    float* h_ln     = ws + o; o += (size_t)M * DMODEL;
    float* xz       = ws + o; o += (size_t)M * 2 * DIN;
    float* xcf      = ws + o; o += (size_t)M * DIN;
    float* xcb      = ws + o; o += (size_t)M * DIN;
    float* xdbf     = ws + o; o += (size_t)M * XDB;
    float* xdbb     = ws + o; o += (size_t)M * XDB;
    float* dtf      = ws + o; o += (size_t)M * DIN;
    float* dtb      = ws + o; o += (size_t)M * DIN;
    float* yfb      = ws + o; o += (size_t)M * DIN;
    float* ybb      = ws + o; o += (size_t)M * DIN;
    float* hpart    = ws + o; o += (size_t)NC * 8 * NST * DIN;
    float* sumd     = ws + o; o += (size_t)NC * 8 * DIN;
    (void)ws_size; (void)in_sizes; (void)n_in; (void)out_size;

    // patchify -> residual (with bias + pos, cls gap)
    gemm_k<1, 3><<<dim3(16, 6), 256, 0, stream>>>(
        nullptr, 0, patch_w, patch_b, residual, 1024, DMODEL, 256,
        depth_seq, nullptr, pos_embed);
    cls_k<<<BB, DMODEL, 0, stream>>>(cls_token, pos_embed, residual);

    for (int i = 0; i < 4; ++i) {
        ln_k<<<M, 128, 0, stream>>>(residual, ln_w + (size_t)i * DMODEL,
                                    ln_b + (size_t)i * DMODEL, h_ln);
        // in_proj: (1028 x 384) @ (384 x 1536)^T
        gemm_pair_k<0><<<dim3(17, 24, 1), 256, 0, stream>>>(
            h_ln, in_proj_w + (size_t)i * 2 * DIN * DMODEL, nullptr, xz,
            h_ln, in_proj_w + (size_t)i * 2 * DIN * DMODEL, nullptr, xz,
            DMODEL, M, 2 * DIN, DMODEL);
        conv_k<<<(BB * LF * DIN) / 256, 256, 0, stream>>>(
            xz, conv_w + (size_t)i * DIN * 4, conv_b + (size_t)i * DIN,
            conv_wb + (size_t)i * DIN * 4, conv_bb + (size_t)i * DIN, xcf, xcb);
        // x_proj fwd+bwd in one dispatch: (1028 x 768) @ (768 x 56)^T
        gemm_pair_k<0><<<dim3(17, 1, 2), 256, 0, stream>>>(
            xcf, xproj_w  + (size_t)i * XDB * DIN, nullptr, xdbf,
            xcb, xproj_wb + (size_t)i * XDB * DIN, nullptr, xdbb,
            DIN, M, XDB, DIN);
        // dt fwd+bwd in one dispatch: (1028 x 24) @ (24 x 768)^T + softplus
        gemm_pair_k<1><<<dim3(17, 12, 2), 256, 0, stream>>>(
            xdbf, dtproj_w  + (size_t)i * DIN * DTR, dtproj_b  + (size_t)i * DIN, dtf,
            xdbb, dtproj_wb + (size_t)i * DIN * DTR, dtproj_bb + (size_t)i * DIN, dtb,
            XDB, M, DIN, DTR);
        // chunked scan: partials then combine+output
        scanA_k<<<dim3(3, 8, NC), 256, 0, stream>>>(
            xcf, dtf, xdbf, xcb, dtb, xdbb,
            A_log + (size_t)i * DIN * NST, A_logb + (size_t)i * DIN * NST,
            hpart, sumd);
        scanC_k<<<dim3(3, 8, NC), 256, 0, stream>>>(
            xcf, dtf, xdbf, xcb, dtb, xdbb, xz,
            A_log + (size_t)i * DIN * NST, Dp + (size_t)i * DIN,
            A_logb + (size_t)i * DIN * NST, Dpb + (size_t)i * DIN,
            hpart, sumd, yfb, ybb);
        // out_proj with fused flip-add, residual +=
        gemm_k<2, 2><<<dim3(17, 6), 256, 0, stream>>>(
            yfb, DIN, out_w + (size_t)i * DMODEL * DIN, nullptr,
            residual, M, DMODEL, DIN, nullptr, ybb, nullptr);
    }

    final_k<<<BB, DMODEL, 0, stream>>>(
        residual, lnf_w, lnf_b, state_vec, action, cw1, cb1, cw2, cb2,
        (float*)d_out);
}